// Round 10
// baseline (3165.490 us; speedup 1.0000x reference)
//
#include <hip/hip_runtime.h>
#include <cstdint>
#include <cstddef>

#define NPTS 4096
#define NP   512
#define NS   32
#define NB   16
#define NTOT (NB*NP*NS)   // 262144 points through the MLP
#define NBLK 1024         // 1024*256 == NTOT

// ---------------- FPS: one wave per batch, f64 decisions; f32 out (B,3,512) ----------------
__global__ __launch_bounds__(64) void fps_v10(const float* __restrict__ xyz,
    float* __restrict__ new_xyz, float* __restrict__ outx)
{
  const int b = blockIdx.x, lane = threadIdx.x;   // 64 threads = 1 wave
  const float* base = xyz + (size_t)b*3*NPTS;
  __shared__ float sx[NPTS], sy[NPTS], sz[NPTS];
  __shared__ double s_v[64];
  __shared__ int    s_i[64];
  __shared__ int    s_far;
  for (int i = lane; i < NPTS; i += 64) {
    sx[i] = base[i]; sy[i] = base[NPTS+i]; sz[i] = base[2*NPTS+i];
  }
  __syncthreads();
  double dist[64];
#pragma unroll
  for (int j = 0; j < 64; ++j) dist[j] = 1e10;
  int far = 0;
  for (int it = 0; it < NP; ++it) {
    float fx = sx[far], fy = sy[far], fz = sz[far];
    double cx = (double)fx, cy = (double)fy, cz = (double)fz;
    if (lane == 0) {
      // pre-update emission: center #it = pts[far]
      float* nx = new_xyz + ((size_t)b*NP + it)*3;
      nx[0] = fx; nx[1] = fy; nx[2] = fz;
      float* o = outx + (size_t)b*3*NP + it;   // (B,3,512) f32
      o[0]    = fx;
      o[NP]   = fy;
      o[2*NP] = fz;
    }
    double bv = -1.0; int bi = 0;
#pragma unroll
    for (int j = 0; j < 64; ++j) {
      const int p = lane*64 + j;   // lane owns contiguous [lane*64, lane*64+64)
      double dx = __dsub_rn((double)sx[p], cx);
      double dy = __dsub_rn((double)sy[p], cy);
      double dz = __dsub_rn((double)sz[p], cz);
      double d  = __dadd_rn(__dadd_rn(__dmul_rn(dx,dx), __dmul_rn(dy,dy)), __dmul_rn(dz,dz));
      d = fmin(dist[j], d);
      dist[j] = d;
      if (d > bv) { bv = d; bi = p; }   // ascending p + strict > = first occurrence
    }
    s_v[lane] = bv; s_i[lane] = bi;
    __syncthreads();
    if (lane == 0) {
      double fv = s_v[0]; int fi = s_i[0];
      for (int l = 1; l < 64; ++l)
        if (s_v[l] > fv) { fv = s_v[l]; fi = s_i[l]; }   // disjoint ascending ranges
      s_far = fi;
    }
    __syncthreads();
    far = s_far;
  }
}

// ---------------- ball query: one wave per center, f64 radius decisions ----------------
__global__ __launch_bounds__(256) void ballq_v10(const float* __restrict__ xyz,
    const float* __restrict__ new_xyz, int* __restrict__ nidx)
{
  const int wid  = (blockIdx.x*256 + threadIdx.x) >> 6;   // 0..8191 = b*512+k
  const int lane = threadIdx.x & 63;
  const int b = wid >> 9;
  const float* base = xyz + (size_t)b*3*NPTS;
  const float* c = new_xyz + (size_t)wid*3;
  double cx = (double)c[0], cy = (double)c[1], cz = (double)c[2];
  int* xi = nidx + (size_t)wid*NS;
  int cnt = 0, first_j = 0;
  for (int jb = 0; jb < NPTS && cnt < NS; jb += 64) {
    int j = jb + lane;
    double dxv = __dsub_rn((double)base[j],        cx);
    double dyv = __dsub_rn((double)base[NPTS+j],   cy);
    double dzv = __dsub_rn((double)base[2*NPTS+j], cz);
    double d = __dadd_rn(__dadd_rn(__dmul_rn(dxv,dxv), __dmul_rn(dyv,dyv)), __dmul_rn(dzv,dzv));
    bool in = !(d > 0.25);
    unsigned long long m = __ballot(in);
    int pos = cnt + __popcll(m & ((1ull<<lane)-1ull));
    if (in && pos < NS) xi[pos] = j;
    if (cnt == 0 && m) first_j = jb + __builtin_ctzll(m);
    cnt += __popcll(m);
  }
  int nv = cnt < NS ? cnt : NS;
  for (int s = nv + lane; s < NS; s += 64) xi[s] = first_j;
}

// ---------------- gather one grouped input row ----------------
__device__ __forceinline__ void load_x0_v10(const float* __restrict__ xyz,
    const float* __restrict__ feat, const float* __restrict__ nxyz,
    const int* __restrict__ nidx, int p, float x[9])
{
  const int wid = p >> 5;            // center id
  const int b   = wid >> 9;
  const int j   = nidx[p];
  const float* base = xyz  + (size_t)b*3*NPTS;
  const float* fb   = feat + (size_t)b*6*NPTS;
  const float* c    = nxyz + (size_t)wid*3;
  x[0] = __fsub_rn(base[j],        c[0]);
  x[1] = __fsub_rn(base[NPTS+j],   c[1]);
  x[2] = __fsub_rn(base[2*NPTS+j], c[2]);
#pragma unroll
  for (int cc = 0; cc < 6; ++cc) x[3+cc] = fb[cc*NPTS + j];
}

// ---------------- layer0 partial sums ----------------
__global__ __launch_bounds__(256) void statsA_v10(const float* __restrict__ xyz,
    const float* __restrict__ feat, const float* __restrict__ nxyz, const int* __restrict__ nidx,
    const float* __restrict__ W0, const float* __restrict__ b0, float* __restrict__ part)
{
  __shared__ float sW[576], sb[64], sS[4][64], sQ[4][64];
  const int t = threadIdx.x;
  for (int i = t; i < 576; i += 256) sW[i] = W0[i];
  if (t < 64) sb[t] = b0[t];
  __syncthreads();
  const int p = blockIdx.x*256 + t;
  float x[9];
  load_x0_v10(xyz, feat, nxyz, nidx, p, x);
  const int wv = t>>6, lane = t&63;
  for (int o = 0; o < 64; ++o) {
    float acc = sb[o];
#pragma unroll
    for (int cc = 0; cc < 9; ++cc) acc = fmaf(sW[o*9+cc], x[cc], acc);
    float s = acc, q = acc*acc;
#pragma unroll
    for (int m = 1; m < 64; m <<= 1) { s += __shfl_xor(s, m, 64); q += __shfl_xor(q, m, 64); }
    if (lane == 0) { sS[wv][o] = s; sQ[wv][o] = q; }
  }
  __syncthreads();
  if (t < 64) {
    part[blockIdx.x*256 + t]       = sS[0][t]+sS[1][t]+sS[2][t]+sS[3][t];
    part[blockIdx.x*256 + 128 + t] = sQ[0][t]+sQ[1][t]+sQ[2][t]+sQ[3][t];
  }
}

// ---------------- finalize stats: partials -> mean/scale/shift (f64 accum) ----------------
__global__ __launch_bounds__(1024) void finalize_v10(const float* __restrict__ part,
    const float* __restrict__ g, const float* __restrict__ beta,
    float* __restrict__ stats, int C)
{
  __shared__ double sS[8][128], sQ[8][128];
  const int t = threadIdx.x, q = t>>7, o = t&127;
  double S = 0.0, Q = 0.0;
  if (o < C) {
    for (int bk = q*128; bk < q*128 + 128; ++bk) {
      S += (double)part[bk*256 + o];
      Q += (double)part[bk*256 + 128 + o];
    }
  }
  sS[q][o] = S; sQ[q][o] = Q;
  __syncthreads();
  if (t < C) {
    double s = 0.0, qq = 0.0;
    for (int i = 0; i < 8; ++i) { s += sS[i][t]; qq += sQ[i][t]; }
    const double invN = 1.0/(double)NTOT;
    double mean = s*invN;
    double var  = qq*invN - mean*mean;
    float sc    = g[t] / (float)sqrt(var + 1e-5);
    stats[t] = (float)mean; stats[C+t] = sc; stats[2*C+t] = beta[t];
  }
}

// ---------------- layer1 partial sums (recompute layer0+bn0) ----------------
__global__ __launch_bounds__(256) void statsB_v10(const float* __restrict__ xyz,
    const float* __restrict__ feat, const float* __restrict__ nxyz, const int* __restrict__ nidx,
    const float* __restrict__ W0, const float* __restrict__ b0, const float* __restrict__ st0,
    const float* __restrict__ W1, const float* __restrict__ b1, float* __restrict__ part)
{
  __shared__ float sW0[576], sb0[64], sm0[64], ss0[64], sB0[64];
  __shared__ float sW1[4096], sb1[64], sS[4][64], sQ[4][64];
  const int t = threadIdx.x;
  for (int i = t; i < 576;  i += 256) sW0[i] = W0[i];
  for (int i = t; i < 4096; i += 256) sW1[i] = W1[i];
  if (t < 64) { sb0[t]=b0[t]; sm0[t]=st0[t]; ss0[t]=st0[64+t]; sB0[t]=st0[128+t]; sb1[t]=b1[t]; }
  __syncthreads();
  const int p = blockIdx.x*256 + t;
  float x[9];
  load_x0_v10(xyz, feat, nxyz, nidx, p, x);
  float x1[64];
#pragma unroll
  for (int o = 0; o < 64; ++o) {
    float acc = sb0[o];
#pragma unroll
    for (int cc = 0; cc < 9; ++cc) acc = fmaf(sW0[o*9+cc], x[cc], acc);
    x1[o] = fmaxf((acc - sm0[o])*ss0[o] + sB0[o], 0.f);
  }
  const int wv = t>>6, lane = t&63;
  for (int o = 0; o < 64; ++o) {
    float acc = sb1[o];
#pragma unroll
    for (int cc = 0; cc < 64; ++cc) acc = fmaf(sW1[o*64+cc], x1[cc], acc);
    float s = acc, qv = acc*acc;
#pragma unroll
    for (int m = 1; m < 64; m <<= 1) { s += __shfl_xor(s, m, 64); qv += __shfl_xor(qv, m, 64); }
    if (lane == 0) { sS[wv][o] = s; sQ[wv][o] = qv; }
  }
  __syncthreads();
  if (t < 64) {
    part[blockIdx.x*256 + t]       = sS[0][t]+sS[1][t]+sS[2][t]+sS[3][t];
    part[blockIdx.x*256 + 128 + t] = sQ[0][t]+sQ[1][t]+sQ[2][t]+sQ[3][t];
  }
}

// ---------------- layer2 partial sums (recompute layers 0,1) ----------------
__global__ __launch_bounds__(256) void statsC_v10(const float* __restrict__ xyz,
    const float* __restrict__ feat, const float* __restrict__ nxyz, const int* __restrict__ nidx,
    const float* __restrict__ W0, const float* __restrict__ b0, const float* __restrict__ st0,
    const float* __restrict__ W1, const float* __restrict__ b1, const float* __restrict__ st1,
    const float* __restrict__ W2, const float* __restrict__ b2, float* __restrict__ part)
{
  __shared__ float sW0[576], sW1[4096], sW2[8192];
  __shared__ float sb0[64], sm0[64], ss0[64], sB0[64];
  __shared__ float sb1[64], sm1[64], ss1[64], sB1[64];
  __shared__ float sb2[128];
  __shared__ float sS[4][128], sQ[4][128];
  const int t = threadIdx.x;
  for (int i = t; i < 576;  i += 256) sW0[i] = W0[i];
  for (int i = t; i < 4096; i += 256) sW1[i] = W1[i];
  for (int i = t; i < 8192; i += 256) sW2[i] = W2[i];
  if (t < 64) {
    sb0[t]=b0[t]; sm0[t]=st0[t]; ss0[t]=st0[64+t]; sB0[t]=st0[128+t];
    sb1[t]=b1[t]; sm1[t]=st1[t]; ss1[t]=st1[64+t]; sB1[t]=st1[128+t];
  }
  if (t < 128) sb2[t] = b2[t];
  __syncthreads();
  const int p = blockIdx.x*256 + t;
  float x[9];
  load_x0_v10(xyz, feat, nxyz, nidx, p, x);
  float x1[64];
#pragma unroll
  for (int o = 0; o < 64; ++o) {
    float acc = sb0[o];
#pragma unroll
    for (int cc = 0; cc < 9; ++cc) acc = fmaf(sW0[o*9+cc], x[cc], acc);
    x1[o] = fmaxf((acc - sm0[o])*ss0[o] + sB0[o], 0.f);
  }
  float x2[64];
#pragma unroll
  for (int o = 0; o < 64; ++o) {
    float acc = sb1[o];
#pragma unroll
    for (int cc = 0; cc < 64; ++cc) acc = fmaf(sW1[o*64+cc], x1[cc], acc);
    x2[o] = fmaxf((acc - sm1[o])*ss1[o] + sB1[o], 0.f);
  }
  const int wv = t>>6, lane = t&63;
  for (int o = 0; o < 128; ++o) {
    float acc = sb2[o];
#pragma unroll
    for (int cc = 0; cc < 64; ++cc) acc = fmaf(sW2[o*64+cc], x2[cc], acc);
    float s = acc, qv = acc*acc;
#pragma unroll
    for (int m = 1; m < 64; m <<= 1) { s += __shfl_xor(s, m, 64); qv += __shfl_xor(qv, m, 64); }
    if (lane == 0) { sS[wv][o] = s; sQ[wv][o] = qv; }
  }
  __syncthreads();
  if (t < 128) {
    part[blockIdx.x*256 + t]       = sS[0][t]+sS[1][t]+sS[2][t]+sS[3][t];
    part[blockIdx.x*256 + 128 + t] = sQ[0][t]+sQ[1][t]+sQ[2][t]+sQ[3][t];
  }
}

// ---------------- final: recompute chain, bn2+relu, max over samples; f32 out ----------------
__global__ __launch_bounds__(256) void final_v10(const float* __restrict__ xyz,
    const float* __restrict__ feat, const float* __restrict__ nxyz, const int* __restrict__ nidx,
    const float* __restrict__ W0, const float* __restrict__ b0, const float* __restrict__ st0,
    const float* __restrict__ W1, const float* __restrict__ b1, const float* __restrict__ st1,
    const float* __restrict__ W2, const float* __restrict__ b2, const float* __restrict__ st2,
    float* __restrict__ outf)
{
  __shared__ float sW0[576], sW1[4096], sW2[8192];
  __shared__ float sb0[64], sm0[64], ss0[64], sB0[64];
  __shared__ float sb1[64], sm1[64], ss1[64], sB1[64];
  __shared__ float sb2[128], sm2[128], ss2[128], sB2[128];
  __shared__ float sx2[8][32][65];   // 8 centers x 32 samples x 64ch (+pad)
  const int t = threadIdx.x;
  for (int i = t; i < 576;  i += 256) sW0[i] = W0[i];
  for (int i = t; i < 4096; i += 256) sW1[i] = W1[i];
  for (int i = t; i < 8192; i += 256) sW2[i] = W2[i];
  if (t < 64) {
    sb0[t]=b0[t]; sm0[t]=st0[t]; ss0[t]=st0[64+t]; sB0[t]=st0[128+t];
    sb1[t]=b1[t]; sm1[t]=st1[t]; ss1[t]=st1[64+t]; sB1[t]=st1[128+t];
  }
  if (t < 128) { sb2[t]=b2[t]; sm2[t]=st2[t]; ss2[t]=st2[128+t]; sB2[t]=st2[256+t]; }
  __syncthreads();
  // phase 1: each thread owns (center c8 = t>>5, sample s = t&31)
  const int c8 = t >> 5, s = t & 31;
  const int bk = blockIdx.x*8 + c8;         // global center id
  const int p  = bk*NS + s;
  float x[9];
  load_x0_v10(xyz, feat, nxyz, nidx, p, x);
  float x1[64];
#pragma unroll
  for (int o = 0; o < 64; ++o) {
    float acc = sb0[o];
#pragma unroll
    for (int cc = 0; cc < 9; ++cc) acc = fmaf(sW0[o*9+cc], x[cc], acc);
    x1[o] = fmaxf((acc - sm0[o])*ss0[o] + sB0[o], 0.f);
  }
#pragma unroll
  for (int o = 0; o < 64; ++o) {
    float acc = sb1[o];
#pragma unroll
    for (int cc = 0; cc < 64; ++cc) acc = fmaf(sW1[o*64+cc], x1[cc], acc);
    sx2[c8][s][o] = fmaxf((acc - sm1[o])*ss1[o] + sB1[o], 0.f);
  }
  __syncthreads();
  // phase 2: thread handles center c8, channels o0..o0+3
  const int o0 = (t & 31) * 4;
  float mx[4] = {0.f, 0.f, 0.f, 0.f};      // relu outputs are >= 0
  for (int s2 = 0; s2 < NS; ++s2) {
    float acc[4];
#pragma unroll
    for (int i = 0; i < 4; ++i) acc[i] = sb2[o0+i];
    for (int cc = 0; cc < 64; ++cc) {
      float xv = sx2[c8][s2][cc];
#pragma unroll
      for (int i = 0; i < 4; ++i) acc[i] = fmaf(sW2[(o0+i)*64 + cc], xv, acc[i]);
    }
#pragma unroll
    for (int i = 0; i < 4; ++i) {
      float v = fmaxf((acc[i] - sm2[o0+i])*ss2[o0+i] + sB2[o0+i], 0.f);
      mx[i] = fmaxf(mx[i], v);
    }
  }
  const int b = bk >> 9, k = bk & 511;
#pragma unroll
  for (int i = 0; i < 4; ++i)
    outf[(size_t)b*(128*512) + (size_t)(o0+i)*512 + k] = mx[i];
}

extern "C" void kernel_launch(void* const* d_in, const int* in_sizes, int n_in,
                              void* d_out, int out_size, void* d_ws, size_t ws_size,
                              hipStream_t stream)
{
  const float* xyz = (const float*)d_in[0];
  const float* feat= (const float*)d_in[1];
  const float* W0  = (const float*)d_in[2];
  const float* b0  = (const float*)d_in[3];
  const float* g0  = (const float*)d_in[4];
  const float* be0 = (const float*)d_in[5];
  const float* W1  = (const float*)d_in[6];
  const float* b1  = (const float*)d_in[7];
  const float* g1  = (const float*)d_in[8];
  const float* be1 = (const float*)d_in[9];
  const float* W2  = (const float*)d_in[10];
  const float* b2  = (const float*)d_in[11];
  const float* g2  = (const float*)d_in[12];
  const float* be2 = (const float*)d_in[13];

  // compact workspace: ~2.2 MB total
  char* ws = (char*)d_ws;
  float* nxyz = (float*)(ws);              // 8192*3*4    = 98304 B
  int*   nidx = (int*)  (ws + 98304);      // 8192*32*4   = 1048576 B
  float* part = (float*)(ws + 1146880);    // 1024*256*4  = 1048576 B
  float* st0  = (float*)(ws + 2195456);
  float* st1  = (float*)(ws + 2196480);
  float* st2  = (float*)(ws + 2197504);

  // d_out is FLOAT32 (established round 9): output 0 = new_xyz (16,3,512),
  // output 1 = new_feat (16,128,512), concatenated flat in return order.
  float* outx = (float*)d_out;
  float* outf = outx + (size_t)16*3*512;

  fps_v10      <<<16,     64, 0, stream>>>(xyz, nxyz, outx);
  ballq_v10    <<<2048, 256, 0, stream>>>(xyz, nxyz, nidx);
  statsA_v10   <<<NBLK, 256, 0, stream>>>(xyz, feat, nxyz, nidx, W0, b0, part);
  finalize_v10 <<<1,   1024, 0, stream>>>(part, g0, be0, st0, 64);
  statsB_v10   <<<NBLK, 256, 0, stream>>>(xyz, feat, nxyz, nidx, W0, b0, st0, W1, b1, part);
  finalize_v10 <<<1,   1024, 0, stream>>>(part, g1, be1, st1, 64);
  statsC_v10   <<<NBLK, 256, 0, stream>>>(xyz, feat, nxyz, nidx, W0, b0, st0, W1, b1, st1, W2, b2, part);
  finalize_v10 <<<1,   1024, 0, stream>>>(part, g2, be2, st2, 128);
  final_v10    <<<NBLK, 256, 0, stream>>>(xyz, feat, nxyz, nidx, W0, b0, st0, W1, b1, st1, W2, b2, st2, outf);
}

// Round 11
// 1445.493 us; speedup vs baseline: 2.1899x; 2.1899x over previous
//
#include <hip/hip_runtime.h>
#include <cstdint>
#include <cstddef>

#define NPTS 4096
#define NP   512
#define NS   32
#define NB   16
#define NTOT (NB*NP*NS)   // 262144 points through the MLP
#define NBLK 1024         // 1024*256 == NTOT

// ---------------- FPS: 256 thr/batch, coords in registers, f32 decisions ----------------
// Stream proven == reference (r2==r3==r4==r6 bitwise; r10 passed with same stream).
__global__ __launch_bounds__(256) void fps_v11(const float* __restrict__ xyz,
    float* __restrict__ new_xyz, float* __restrict__ outx)
{
  const int b = blockIdx.x, t = threadIdx.x;
  const float* base = xyz + (size_t)b*3*NPTS;
  __shared__ float sx[NPTS], sy[NPTS], sz[NPTS];   // centroid lookup only
  __shared__ float s_v[4];
  __shared__ int   s_i[4];
  __shared__ int   s_far;
  float px[16], py[16], pz[16], dist[16];
#pragma unroll
  for (int q = 0; q < 16; ++q) {
    const int p = t + q*256;                       // strided ownership
    px[q] = base[p]; py[q] = base[NPTS+p]; pz[q] = base[2*NPTS+p];
    sx[p] = px[q]; sy[p] = py[q]; sz[p] = pz[q];
    dist[q] = 1e10f;
  }
  __syncthreads();
  int far = 0;
  for (int it = 0; it < NP; ++it) {
    const float cx = sx[far], cy = sy[far], cz = sz[far];
    if (t == 0) {
      // pre-update emission: center #it = pts[far]
      float* nx = new_xyz + ((size_t)b*NP + it)*3;
      nx[0] = cx; nx[1] = cy; nx[2] = cz;
      float* o = outx + (size_t)b*3*NP + it;       // (B,3,512) f32
      o[0] = cx; o[NP] = cy; o[2*NP] = cz;
    }
    float bv = -1.f; int bi = 0;
#pragma unroll
    for (int q = 0; q < 16; ++q) {
      // exact f32, numpy sum order ((dx^2+dy^2)+dz^2), no FMA contraction
      float dx = __fsub_rn(px[q], cx);
      float dy = __fsub_rn(py[q], cy);
      float dz = __fsub_rn(pz[q], cz);
      float d  = __fadd_rn(__fadd_rn(__fmul_rn(dx,dx), __fmul_rn(dy,dy)), __fmul_rn(dz,dz));
      d = fminf(dist[q], d);
      dist[q] = d;
      if (d > bv) { bv = d; bi = t + q*256; }      // ascending q: strict > keeps first
    }
#pragma unroll
    for (int m = 1; m < 64; m <<= 1) {             // wave butterfly, idx tie-break
      float ov = __shfl_xor(bv, m, 64);
      int   oi = __shfl_xor(bi, m, 64);
      if (ov > bv || (ov == bv && oi < bi)) { bv = ov; bi = oi; }
    }
    if ((t & 63) == 0) { s_v[t>>6] = bv; s_i[t>>6] = bi; }
    __syncthreads();
    if (t == 0) {
      float fv = s_v[0]; int fi = s_i[0];
      for (int w = 1; w < 4; ++w)
        if (s_v[w] > fv || (s_v[w] == fv && s_i[w] < fi)) { fv = s_v[w]; fi = s_i[w]; }
      s_far = fi;
    }
    __syncthreads();
    far = s_far;
  }
}

// ---------------- ball query: one wave per center, f64 radius decisions (unchanged) ----------------
__global__ __launch_bounds__(256) void ballq_v11(const float* __restrict__ xyz,
    const float* __restrict__ new_xyz, int* __restrict__ nidx)
{
  const int wid  = (blockIdx.x*256 + threadIdx.x) >> 6;   // 0..8191 = b*512+k
  const int lane = threadIdx.x & 63;
  const int b = wid >> 9;
  const float* base = xyz + (size_t)b*3*NPTS;
  const float* c = new_xyz + (size_t)wid*3;
  double cx = (double)c[0], cy = (double)c[1], cz = (double)c[2];
  int* xi = nidx + (size_t)wid*NS;
  int cnt = 0, first_j = 0;
  for (int jb = 0; jb < NPTS && cnt < NS; jb += 64) {
    int j = jb + lane;
    double dxv = __dsub_rn((double)base[j],        cx);
    double dyv = __dsub_rn((double)base[NPTS+j],   cy);
    double dzv = __dsub_rn((double)base[2*NPTS+j], cz);
    double d = __dadd_rn(__dadd_rn(__dmul_rn(dxv,dxv), __dmul_rn(dyv,dyv)), __dmul_rn(dzv,dzv));
    bool in = !(d > 0.25);
    unsigned long long m = __ballot(in);
    int pos = cnt + __popcll(m & ((1ull<<lane)-1ull));
    if (in && pos < NS) xi[pos] = j;
    if (cnt == 0 && m) first_j = jb + __builtin_ctzll(m);
    cnt += __popcll(m);
  }
  int nv = cnt < NS ? cnt : NS;
  for (int s = nv + lane; s < NS; s += 64) xi[s] = first_j;
}

// ---------------- gather one grouped input row ----------------
__device__ __forceinline__ void load_x0_v11(const float* __restrict__ xyz,
    const float* __restrict__ feat, const float* __restrict__ nxyz,
    const int* __restrict__ nidx, int p, float x[9])
{
  const int wid = p >> 5;            // center id
  const int b   = wid >> 9;
  const int j   = nidx[p];
  const float* base = xyz  + (size_t)b*3*NPTS;
  const float* fb   = feat + (size_t)b*6*NPTS;
  const float* c    = nxyz + (size_t)wid*3;
  x[0] = __fsub_rn(base[j],        c[0]);
  x[1] = __fsub_rn(base[NPTS+j],   c[1]);
  x[2] = __fsub_rn(base[2*NPTS+j], c[2]);
#pragma unroll
  for (int cc = 0; cc < 6; ++cc) x[3+cc] = fb[cc*NPTS + j];
}

// ---------------- layer0 partial sums ----------------
__global__ __launch_bounds__(256) void statsA_v11(const float* __restrict__ xyz,
    const float* __restrict__ feat, const float* __restrict__ nxyz, const int* __restrict__ nidx,
    const float* __restrict__ W0, const float* __restrict__ b0, float* __restrict__ part)
{
  __shared__ float sW[576], sb[64], sS[4][64], sQ[4][64];
  const int t = threadIdx.x;
  for (int i = t; i < 576; i += 256) sW[i] = W0[i];
  if (t < 64) sb[t] = b0[t];
  __syncthreads();
  const int p = blockIdx.x*256 + t;
  float x[9];
  load_x0_v11(xyz, feat, nxyz, nidx, p, x);
  const int wv = t>>6, lane = t&63;
  for (int o = 0; o < 64; ++o) {
    float acc = sb[o];
#pragma unroll
    for (int cc = 0; cc < 9; ++cc) acc = fmaf(sW[o*9+cc], x[cc], acc);
    float s = acc, q = acc*acc;
#pragma unroll
    for (int m = 1; m < 64; m <<= 1) { s += __shfl_xor(s, m, 64); q += __shfl_xor(q, m, 64); }
    if (lane == 0) { sS[wv][o] = s; sQ[wv][o] = q; }
  }
  __syncthreads();
  if (t < 64) {
    part[blockIdx.x*256 + t]       = sS[0][t]+sS[1][t]+sS[2][t]+sS[3][t];
    part[blockIdx.x*256 + 128 + t] = sQ[0][t]+sQ[1][t]+sQ[2][t]+sQ[3][t];
  }
}

// ---------------- finalize stats: partials -> mean/scale/shift (f64 accum) ----------------
__global__ __launch_bounds__(1024) void finalize_v11(const float* __restrict__ part,
    const float* __restrict__ g, const float* __restrict__ beta,
    float* __restrict__ stats, int C)
{
  __shared__ double sS[8][128], sQ[8][128];
  const int t = threadIdx.x, q = t>>7, o = t&127;
  double S = 0.0, Q = 0.0;
  if (o < C) {
    for (int bk = q*128; bk < q*128 + 128; ++bk) {
      S += (double)part[bk*256 + o];
      Q += (double)part[bk*256 + 128 + o];
    }
  }
  sS[q][o] = S; sQ[q][o] = Q;
  __syncthreads();
  if (t < C) {
    double s = 0.0, qq = 0.0;
    for (int i = 0; i < 8; ++i) { s += sS[i][t]; qq += sQ[i][t]; }
    const double invN = 1.0/(double)NTOT;
    double mean = s*invN;
    double var  = qq*invN - mean*mean;
    float sc    = g[t] / (float)sqrt(var + 1e-5);
    stats[t] = (float)mean; stats[C+t] = sc; stats[2*C+t] = beta[t];
  }
}

// ---------------- layer1 partial sums (recompute layer0+bn0) ----------------
__global__ __launch_bounds__(256) void statsB_v11(const float* __restrict__ xyz,
    const float* __restrict__ feat, const float* __restrict__ nxyz, const int* __restrict__ nidx,
    const float* __restrict__ W0, const float* __restrict__ b0, const float* __restrict__ st0,
    const float* __restrict__ W1, const float* __restrict__ b1, float* __restrict__ part)
{
  __shared__ float sW0[576], sb0[64], sm0[64], ss0[64], sB0[64];
  __shared__ float sW1[4096], sb1[64], sS[4][64], sQ[4][64];
  const int t = threadIdx.x;
  for (int i = t; i < 576;  i += 256) sW0[i] = W0[i];
  for (int i = t; i < 4096; i += 256) sW1[i] = W1[i];
  if (t < 64) { sb0[t]=b0[t]; sm0[t]=st0[t]; ss0[t]=st0[64+t]; sB0[t]=st0[128+t]; sb1[t]=b1[t]; }
  __syncthreads();
  const int p = blockIdx.x*256 + t;
  float x[9];
  load_x0_v11(xyz, feat, nxyz, nidx, p, x);
  float x1[64];
#pragma unroll
  for (int o = 0; o < 64; ++o) {
    float acc = sb0[o];
#pragma unroll
    for (int cc = 0; cc < 9; ++cc) acc = fmaf(sW0[o*9+cc], x[cc], acc);
    x1[o] = fmaxf((acc - sm0[o])*ss0[o] + sB0[o], 0.f);
  }
  const int wv = t>>6, lane = t&63;
  for (int o = 0; o < 64; ++o) {
    float acc = sb1[o];
#pragma unroll
    for (int cc = 0; cc < 64; ++cc) acc = fmaf(sW1[o*64+cc], x1[cc], acc);
    float s = acc, qv = acc*acc;
#pragma unroll
    for (int m = 1; m < 64; m <<= 1) { s += __shfl_xor(s, m, 64); qv += __shfl_xor(qv, m, 64); }
    if (lane == 0) { sS[wv][o] = s; sQ[wv][o] = qv; }
  }
  __syncthreads();
  if (t < 64) {
    part[blockIdx.x*256 + t]       = sS[0][t]+sS[1][t]+sS[2][t]+sS[3][t];
    part[blockIdx.x*256 + 128 + t] = sQ[0][t]+sQ[1][t]+sQ[2][t]+sQ[3][t];
  }
}

// ---------------- layer2 partial sums (recompute layers 0,1) ----------------
__global__ __launch_bounds__(256) void statsC_v11(const float* __restrict__ xyz,
    const float* __restrict__ feat, const float* __restrict__ nxyz, const int* __restrict__ nidx,
    const float* __restrict__ W0, const float* __restrict__ b0, const float* __restrict__ st0,
    const float* __restrict__ W1, const float* __restrict__ b1, const float* __restrict__ st1,
    const float* __restrict__ W2, const float* __restrict__ b2, float* __restrict__ part)
{
  __shared__ float sW0[576], sW1[4096], sW2[8192];
  __shared__ float sb0[64], sm0[64], ss0[64], sB0[64];
  __shared__ float sb1[64], sm1[64], ss1[64], sB1[64];
  __shared__ float sb2[128];
  __shared__ float sS[4][128], sQ[4][128];
  const int t = threadIdx.x;
  for (int i = t; i < 576;  i += 256) sW0[i] = W0[i];
  for (int i = t; i < 4096; i += 256) sW1[i] = W1[i];
  for (int i = t; i < 8192; i += 256) sW2[i] = W2[i];
  if (t < 64) {
    sb0[t]=b0[t]; sm0[t]=st0[t]; ss0[t]=st0[64+t]; sB0[t]=st0[128+t];
    sb1[t]=b1[t]; sm1[t]=st1[t]; ss1[t]=st1[64+t]; sB1[t]=st1[128+t];
  }
  if (t < 128) sb2[t] = b2[t];
  __syncthreads();
  const int p = blockIdx.x*256 + t;
  float x[9];
  load_x0_v11(xyz, feat, nxyz, nidx, p, x);
  float x1[64];
#pragma unroll
  for (int o = 0; o < 64; ++o) {
    float acc = sb0[o];
#pragma unroll
    for (int cc = 0; cc < 9; ++cc) acc = fmaf(sW0[o*9+cc], x[cc], acc);
    x1[o] = fmaxf((acc - sm0[o])*ss0[o] + sB0[o], 0.f);
  }
  float x2[64];
#pragma unroll
  for (int o = 0; o < 64; ++o) {
    float acc = sb1[o];
#pragma unroll
    for (int cc = 0; cc < 64; ++cc) acc = fmaf(sW1[o*64+cc], x1[cc], acc);
    x2[o] = fmaxf((acc - sm1[o])*ss1[o] + sB1[o], 0.f);
  }
  const int wv = t>>6, lane = t&63;
  for (int o = 0; o < 128; ++o) {
    float acc = sb2[o];
#pragma unroll
    for (int cc = 0; cc < 64; ++cc) acc = fmaf(sW2[o*64+cc], x2[cc], acc);
    float s = acc, qv = acc*acc;
#pragma unroll
    for (int m = 1; m < 64; m <<= 1) { s += __shfl_xor(s, m, 64); qv += __shfl_xor(qv, m, 64); }
    if (lane == 0) { sS[wv][o] = s; sQ[wv][o] = qv; }
  }
  __syncthreads();
  if (t < 128) {
    part[blockIdx.x*256 + t]       = sS[0][t]+sS[1][t]+sS[2][t]+sS[3][t];
    part[blockIdx.x*256 + 128 + t] = sQ[0][t]+sQ[1][t]+sQ[2][t]+sQ[3][t];
  }
}

// ---------------- final: recompute chain, bn2+relu, max over samples; f32 out ----------------
__global__ __launch_bounds__(256) void final_v11(const float* __restrict__ xyz,
    const float* __restrict__ feat, const float* __restrict__ nxyz, const int* __restrict__ nidx,
    const float* __restrict__ W0, const float* __restrict__ b0, const float* __restrict__ st0,
    const float* __restrict__ W1, const float* __restrict__ b1, const float* __restrict__ st1,
    const float* __restrict__ W2, const float* __restrict__ b2, const float* __restrict__ st2,
    float* __restrict__ outf)
{
  __shared__ float sW0[576], sW1[4096], sW2[8192];
  __shared__ float sb0[64], sm0[64], ss0[64], sB0[64];
  __shared__ float sb1[64], sm1[64], ss1[64], sB1[64];
  __shared__ float sb2[128], sm2[128], ss2[128], sB2[128];
  __shared__ float sx2[8][32][65];   // 8 centers x 32 samples x 64ch (+pad)
  const int t = threadIdx.x;
  for (int i = t; i < 576;  i += 256) sW0[i] = W0[i];
  for (int i = t; i < 4096; i += 256) sW1[i] = W1[i];
  for (int i = t; i < 8192; i += 256) sW2[i] = W2[i];
  if (t < 64) {
    sb0[t]=b0[t]; sm0[t]=st0[t]; ss0[t]=st0[64+t]; sB0[t]=st0[128+t];
    sb1[t]=b1[t]; sm1[t]=st1[t]; ss1[t]=st1[64+t]; sB1[t]=st1[128+t];
  }
  if (t < 128) { sb2[t]=b2[t]; sm2[t]=st2[t]; ss2[t]=st2[128+t]; sB2[t]=st2[256+t]; }
  __syncthreads();
  // phase 1: each thread owns (center c8 = t>>5, sample s = t&31)
  const int c8 = t >> 5, s = t & 31;
  const int bk = blockIdx.x*8 + c8;         // global center id
  const int p  = bk*NS + s;
  float x[9];
  load_x0_v11(xyz, feat, nxyz, nidx, p, x);
  float x1[64];
#pragma unroll
  for (int o = 0; o < 64; ++o) {
    float acc = sb0[o];
#pragma unroll
    for (int cc = 0; cc < 9; ++cc) acc = fmaf(sW0[o*9+cc], x[cc], acc);
    x1[o] = fmaxf((acc - sm0[o])*ss0[o] + sB0[o], 0.f);
  }
#pragma unroll
  for (int o = 0; o < 64; ++o) {
    float acc = sb1[o];
#pragma unroll
    for (int cc = 0; cc < 64; ++cc) acc = fmaf(sW1[o*64+cc], x1[cc], acc);
    sx2[c8][s][o] = fmaxf((acc - sm1[o])*ss1[o] + sB1[o], 0.f);
  }
  __syncthreads();
  // phase 2: thread handles center c8, channels o0..o0+3
  const int o0 = (t & 31) * 4;
  float mx[4] = {0.f, 0.f, 0.f, 0.f};      // relu outputs are >= 0
  for (int s2 = 0; s2 < NS; ++s2) {
    float acc[4];
#pragma unroll
    for (int i = 0; i < 4; ++i) acc[i] = sb2[o0+i];
    for (int cc = 0; cc < 64; ++cc) {
      float xv = sx2[c8][s2][cc];
#pragma unroll
      for (int i = 0; i < 4; ++i) acc[i] = fmaf(sW2[(o0+i)*64 + cc], xv, acc[i]);
    }
#pragma unroll
    for (int i = 0; i < 4; ++i) {
      float v = fmaxf((acc[i] - sm2[o0+i])*ss2[o0+i] + sB2[o0+i], 0.f);
      mx[i] = fmaxf(mx[i], v);
    }
  }
  const int b = bk >> 9, k = bk & 511;
#pragma unroll
  for (int i = 0; i < 4; ++i)
    outf[(size_t)b*(128*512) + (size_t)(o0+i)*512 + k] = mx[i];
}

extern "C" void kernel_launch(void* const* d_in, const int* in_sizes, int n_in,
                              void* d_out, int out_size, void* d_ws, size_t ws_size,
                              hipStream_t stream)
{
  const float* xyz = (const float*)d_in[0];
  const float* feat= (const float*)d_in[1];
  const float* W0  = (const float*)d_in[2];
  const float* b0  = (const float*)d_in[3];
  const float* g0  = (const float*)d_in[4];
  const float* be0 = (const float*)d_in[5];
  const float* W1  = (const float*)d_in[6];
  const float* b1  = (const float*)d_in[7];
  const float* g1  = (const float*)d_in[8];
  const float* be1 = (const float*)d_in[9];
  const float* W2  = (const float*)d_in[10];
  const float* b2  = (const float*)d_in[11];
  const float* g2  = (const float*)d_in[12];
  const float* be2 = (const float*)d_in[13];

  // compact workspace: ~2.2 MB total
  char* ws = (char*)d_ws;
  float* nxyz = (float*)(ws);              // 8192*3*4    = 98304 B
  int*   nidx = (int*)  (ws + 98304);      // 8192*32*4   = 1048576 B
  float* part = (float*)(ws + 1146880);    // 1024*256*4  = 1048576 B
  float* st0  = (float*)(ws + 2195456);
  float* st1  = (float*)(ws + 2196480);
  float* st2  = (float*)(ws + 2197504);

  // d_out is FLOAT32: output 0 = new_xyz (16,3,512), output 1 = new_feat (16,128,512).
  float* outx = (float*)d_out;
  float* outf = outx + (size_t)16*3*512;

  fps_v11      <<<16,   256, 0, stream>>>(xyz, nxyz, outx);
  ballq_v11    <<<2048, 256, 0, stream>>>(xyz, nxyz, nidx);
  statsA_v11   <<<NBLK, 256, 0, stream>>>(xyz, feat, nxyz, nidx, W0, b0, part);
  finalize_v11 <<<1,   1024, 0, stream>>>(part, g0, be0, st0, 64);
  statsB_v11   <<<NBLK, 256, 0, stream>>>(xyz, feat, nxyz, nidx, W0, b0, st0, W1, b1, part);
  finalize_v11 <<<1,   1024, 0, stream>>>(part, g1, be1, st1, 64);
  statsC_v11   <<<NBLK, 256, 0, stream>>>(xyz, feat, nxyz, nidx, W0, b0, st0, W1, b1, st1, W2, b2, part);
  finalize_v11 <<<1,   1024, 0, stream>>>(part, g2, be2, st2, 128);
  final_v11    <<<NBLK, 256, 0, stream>>>(xyz, feat, nxyz, nidx, W0, b0, st0, W1, b1, st1, W2, b2, st2, outf);
}